// Round 19
// baseline (137.170 us; speedup 1.0000x reference)
//
#include <hip/hip_runtime.h>
#include <hip/hip_bf16.h>

#define BATCH 16
#define SEQ   4096
#define DH    64
#define KVB   64
#define NT    (SEQ / KVB)       // 64 tiles
#define LDK   72                // prepass LDS stride (bf16 elems)

using frag   = __attribute__((ext_vector_type(8))) short;
using f32x16 = __attribute__((ext_vector_type(16))) float;
using u16x8  = __attribute__((ext_vector_type(8))) unsigned short;

__device__ __forceinline__ unsigned short f2bf(float x) {
    union { __hip_bfloat16 h; unsigned short u; } cv;
    cv.h = __float2bfloat16(x);
    return cv.u;
}
__device__ __forceinline__ float bf2f(unsigned short u) {
    union { unsigned int i; float f; } cv;
    cv.i = ((unsigned int)u) << 16;
    return cv.f;
}
__device__ __forceinline__ float fast_exp2(float x) {
#if __has_builtin(__builtin_amdgcn_exp2f)
    return __builtin_amdgcn_exp2f(x);
#else
    float r; asm("v_exp_f32 %0, %1" : "=v"(r) : "v"(x)); return r;
#endif
}
__device__ __forceinline__ unsigned int cvtpk_bf16(float lo, float hi) {
    unsigned int r;
    asm("v_cvt_pk_bf16_f32 %0, %1, %2" : "=v"(r) : "v"(lo), "v"(hi));
    return r;
}
__device__ __forceinline__ void glds16(const unsigned short* g, unsigned short* l) {
    __builtin_amdgcn_global_load_lds(
        (const __attribute__((address_space(1))) void*)g,
        (__attribute__((address_space(3))) void*)l, 16, 0, 0);
}
__device__ __forceinline__ f32x16 mfma32(frag a, frag b, f32x16 c) {
    return __builtin_amdgcn_mfma_f32_32x32x16_bf16(a, b, c, 0, 0, 0);
}

// ---------- fused pre-pass: K -> bf16 frag-major, V -> bf16 V^T frag-major ----------
// blocks [0, B*64)            : K tile (b,t) -> Kws [b][t][f=kstep*2+kb][lane][8]
// blocks [B*64, 2*B*64)       : V tile (b,t) -> Vws [b][t][fv=(kb*2+ks)*2+dblk][lane][8]
__global__ __launch_bounds__(256) void prep_kv(const float* __restrict__ K,
                                               const float* __restrict__ V,
                                               unsigned short* __restrict__ Kws,
                                               unsigned short* __restrict__ Vws) {
    __shared__ unsigned short Ls[64 * LDK];
    const bool isV = blockIdx.x >= (BATCH * 64);
    const int  bt  = isV ? (blockIdx.x - BATCH * 64) : blockIdx.x;
    const int b = bt >> 6;
    const int t = bt & 63;
    const int i = threadIdx.x;
    {
        const int kv = i >> 2, db = (i & 3) * 16;
        const float* src = (isV ? V : K) + ((size_t)b * SEQ + (size_t)t * 64 + kv) * DH + db;
        float4 a = *(const float4*)(src);
        float4 c = *(const float4*)(src + 4);
        float4 d = *(const float4*)(src + 8);
        float4 e = *(const float4*)(src + 12);
        u16x8 w0, w1;
        w0[0]=f2bf(a.x); w0[1]=f2bf(a.y); w0[2]=f2bf(a.z); w0[3]=f2bf(a.w);
        w0[4]=f2bf(c.x); w0[5]=f2bf(c.y); w0[6]=f2bf(c.z); w0[7]=f2bf(c.w);
        w1[0]=f2bf(d.x); w1[1]=f2bf(d.y); w1[2]=f2bf(d.z); w1[3]=f2bf(d.w);
        w1[4]=f2bf(e.x); w1[5]=f2bf(e.y); w1[6]=f2bf(e.z); w1[7]=f2bf(e.w);
        *(u16x8*)&Ls[kv * LDK + db]     = w0;
        *(u16x8*)&Ls[kv * LDK + db + 8] = w1;
    }
    __syncthreads();
    if (!isV) {   // K frag gather (row reads) + coalesced 32B store
        const int flat0 = i * 2;
        const int f     = flat0 >> 6;
        const int kb    = f & 1, kstep = f >> 1;
        const int l0    = flat0 & 63, l1 = l0 + 1;
        u16x8 o0 = *(const u16x8*)&Ls[(kb*32 + (l0&31)) * LDK + kstep*16 + (l0>>5)*8];
        u16x8 o1 = *(const u16x8*)&Ls[(kb*32 + (l1&31)) * LDK + kstep*16 + (l1>>5)*8];
        unsigned short* dst = Kws + ((((size_t)b*64 + t)*8 + f)*64 + l0)*8;
        *(u16x8*)dst       = o0;
        *(u16x8*)(dst + 8) = o1;
    } else {      // V^T frag gather (column reads) + coalesced 32B store
        const int flat0 = i * 2;
        const int fv    = flat0 >> 6;
        const int kb    = fv >> 2, ks = (fv >> 1) & 1, dblk = fv & 1;
        u16x8 o0, o1;
        const int l0 = flat0 & 63, l1 = l0 + 1;
#pragma unroll
        for (int j = 0; j < 8; ++j)
            o0[j] = Ls[(kb*32 + ks*16 + (l0>>5)*8 + j) * LDK + dblk*32 + (l0&31)];
#pragma unroll
        for (int j = 0; j < 8; ++j)
            o1[j] = Ls[(kb*32 + ks*16 + (l1>>5)*8 + j) * LDK + dblk*32 + (l1&31)];
        unsigned short* dst = Vws + ((((size_t)b*64 + t)*8 + fv)*64 + l0)*8;
        *(u16x8*)dst       = o0;
        *(u16x8*)(dst + 8) = o1;
    }
}

// ---------- main attention kernel ----------
// K via LDS staging (consumed first; glds dbuf). V loaded DIRECTLY global->
// registers from frag-major layout (coalesced 1KB/instr, L2-resident; issued
// at tile top, consumed last -> latency hides under QK+exp; removes V from
// the LDS pipe, which was the binding ~48us/CU budget).
__global__ __launch_bounds__(256, 4) void attn_fwd(
    const float* __restrict__ Q, const unsigned short* __restrict__ Kws,
    const unsigned short* __restrict__ Vws, const float* __restrict__ S,
    float* __restrict__ O0, unsigned short* __restrict__ O0b,
    unsigned short* __restrict__ O1b,
    float* __restrict__ l0p, float* __restrict__ l1p, int nsplit)
{
    __shared__ unsigned short Kbuf[2][8 * 64 * 8];   // 16 KB total

    const int bid = blockIdx.x;
    const int xcd = bid & 7;
    int sub = bid >> 3;
    int half = 0;
    if (nsplit == 2) { half = sub & 1; sub >>= 1; }
    const int batch = xcd | ((sub & 1) << 3);
    const int qt    = sub >> 1;                      // 0..31, 128 q rows per block

    const int tid  = threadIdx.x;
    const int w    = tid >> 6;                       // wave 0..3, owns 32 q rows
    const int lane = tid & 63;
    const int c32  = lane & 31;
    const int hi   = lane >> 5;

    const int t0   = half * (NT / 2);
    const int ntil = NT / nsplit;

    const float sc = S[0] * 1.44269504088896340736f;

    const float*          Qb = Q   + ((size_t)batch * SEQ + (size_t)qt * 128 + w * 32) * DH;
    const unsigned short* Kg = Kws + (size_t)batch * 64 * 8 * 512;
    const unsigned short* Vg = Vws + (size_t)batch * 64 * 8 * 512;

    frag qF[4];
#pragma unroll
    for (int kstep = 0; kstep < 4; ++kstep) {
        const float* p = Qb + c32 * DH + kstep * 16 + hi * 8;
        float4 a = *(const float4*)p;
        float4 b = *(const float4*)(p + 4);
        frag f;
        f[0] = (short)f2bf(a.x * sc); f[1] = (short)f2bf(a.y * sc);
        f[2] = (short)f2bf(a.z * sc); f[3] = (short)f2bf(a.w * sc);
        f[4] = (short)f2bf(b.x * sc); f[5] = (short)f2bf(b.y * sc);
        f[6] = (short)f2bf(b.z * sc); f[7] = (short)f2bf(b.w * sc);
        qF[kstep] = f;
    }

    frag ones;
#pragma unroll
    for (int j = 0; j < 8; ++j) ones[j] = (short)0x3F80;

    f32x16 o32[2];
    f32x16 l32;
    o32[0] = (f32x16)0.0f; o32[1] = (f32x16)0.0f; l32 = (f32x16)0.0f;

    // K staging: wave w stages K frags {2w,2w+1}
    const int fbase = w * 2;
#pragma unroll
    for (int f = 0; f < 2; ++f)
        glds16(Kg + (size_t)t0 * 4096 + (fbase + f) * 512 + lane * 8, &Kbuf[0][(fbase + f) * 512]);
    asm volatile("s_waitcnt vmcnt(0)" ::: "memory");
    __builtin_amdgcn_s_barrier();
    __builtin_amdgcn_sched_barrier(0);

    for (int tt = 0; tt < ntil; ++tt) {
        const int t   = t0 + tt;
        const int cur = tt & 1;

        // ---- V(t) frags: direct global->register, coalesced (issued early,
        //      consumed at PV; L2 latency hides under QK+exp) ----
        const unsigned short* Vt = Vg + (size_t)t * 4096;
        frag vf[8];
#pragma unroll
        for (int f = 0; f < 8; ++f)
            vf[f] = *(const frag*)(Vt + f * 512 + lane * 8);

        if (tt + 1 < ntil) {     // async K(t+1) -> other buffer
#pragma unroll
            for (int f = 0; f < 2; ++f)
                glds16(Kg + (size_t)(t + 1) * 4096 + (fbase + f) * 512 + lane * 8,
                       &Kbuf[cur ^ 1][(fbase + f) * 512]);
        }

        // ---- QK^T (swapped, 32x32x16): lane holds P^T[kv][q=c32] ----
        f32x16 st[2];
        st[0] = (f32x16)0.0f; st[1] = (f32x16)0.0f;
#pragma unroll
        for (int kstep = 0; kstep < 4; ++kstep)
#pragma unroll
          for (int kb = 0; kb < 2; ++kb) {
            frag kf = *(const frag*)&Kbuf[cur][(kstep * 2 + kb) * 512 + lane * 8];
            st[kb] = mfma32(kf, qF[kstep], st[kb]);
          }

        // ---- native exp2 + cvt_pk + permlane32_swap -> PV A-frags ----
        frag pa[2][2];
#pragma unroll
        for (int kb = 0; kb < 2; ++kb) {
            float p[16];
#pragma unroll
            for (int r = 0; r < 16; ++r) p[r] = fast_exp2(st[kb][r]);
            unsigned a0 = cvtpk_bf16(p[0],  p[1]),  a1 = cvtpk_bf16(p[2],  p[3]);
            unsigned b0 = cvtpk_bf16(p[4],  p[5]),  b1 = cvtpk_bf16(p[6],  p[7]);
            unsigned c0 = cvtpk_bf16(p[8],  p[9]),  c1 = cvtpk_bf16(p[10], p[11]);
            unsigned d0 = cvtpk_bf16(p[12], p[13]), d1 = cvtpk_bf16(p[14], p[15]);
            asm("v_permlane32_swap_b32 %0, %1" : "+v"(a0), "+v"(b0));
            asm("v_permlane32_swap_b32 %0, %1" : "+v"(a1), "+v"(b1));
            asm("v_permlane32_swap_b32 %0, %1" : "+v"(c0), "+v"(d0));
            asm("v_permlane32_swap_b32 %0, %1" : "+v"(c1), "+v"(d1));
            union { unsigned u[4]; frag f; } f0, f1;
            f0.u[0] = a0; f0.u[1] = a1; f0.u[2] = b0; f0.u[3] = b1;
            f1.u[0] = c0; f1.u[1] = c1; f1.u[2] = d0; f1.u[3] = d1;
            pa[kb][0] = f0.f;
            pa[kb][1] = f1.f;
        }

        // ---- row-sum (ones-MFMA) + PV (V from registers) ----
#pragma unroll
        for (int kb = 0; kb < 2; ++kb)
#pragma unroll
          for (int ks = 0; ks < 2; ++ks) {
            l32 = mfma32(pa[kb][ks], ones, l32);
#pragma unroll
            for (int dblk = 0; dblk < 2; ++dblk)
                o32[dblk] = mfma32(pa[kb][ks], vf[(kb * 2 + ks) * 2 + dblk], o32[dblk]);
          }

        asm volatile("s_waitcnt vmcnt(0)" ::: "memory");
        __builtin_amdgcn_s_barrier();
        __builtin_amdgcn_sched_barrier(0);
    }

    // ---- epilogue: row q = (r&3)+8*(r>>2)+4*hi, col d = dblk*32+c32 ----
    const size_t qrow0 = (size_t)batch * SEQ + (size_t)qt * 128 + w * 32;
    if (nsplit == 1) {
        float* Ob = O0 + qrow0 * DH;
        float inv[16];
#pragma unroll
        for (int r = 0; r < 16; ++r) inv[r] = 1.0f / l32[r];
#pragma unroll
        for (int dblk = 0; dblk < 2; ++dblk)
#pragma unroll
          for (int r = 0; r < 16; ++r) {
            const int qrow = (r & 3) + 8 * (r >> 2) + 4 * hi;
            Ob[qrow * DH + dblk * 32 + c32] = o32[dblk][r] * inv[r];
          }
    } else {
        unsigned short* Ob = (half ? O1b : O0b) + qrow0 * DH;
        float* lb = (half ? l1p : l0p) + qrow0;
#pragma unroll
        for (int dblk = 0; dblk < 2; ++dblk)
#pragma unroll
          for (int r = 0; r < 16; ++r) {
            const int qrow = (r & 3) + 8 * (r >> 2) + 4 * hi;
            Ob[qrow * DH + dblk * 32 + c32] = f2bf(o32[dblk][r]);
          }
        if (c32 == 0) {
#pragma unroll
            for (int r = 0; r < 16; ++r) {
                const int qrow = (r & 3) + 8 * (r >> 2) + 4 * hi;
                lb[qrow] = l32[r];
            }
        }
    }
}

// ---------- merge: O = (bf2f(O0b) + bf2f(O1b)) / (l0 + l1) ----------
__global__ __launch_bounds__(256) void merge_halves(
    float* __restrict__ O, const unsigned short* __restrict__ O0b,
    const unsigned short* __restrict__ O1b,
    const float* __restrict__ l0, const float* __restrict__ l1)
{
    const size_t i0  = ((size_t)blockIdx.x * 256 + threadIdx.x) * 8;
    const size_t row = i0 >> 6;
    const float inv  = 1.0f / (l0[row] + l1[row]);
    u16x8 a = *(const u16x8*)(O0b + i0);
    u16x8 b = *(const u16x8*)(O1b + i0);
    float4 r0, r1;
    r0.x = (bf2f(a[0]) + bf2f(b[0])) * inv;
    r0.y = (bf2f(a[1]) + bf2f(b[1])) * inv;
    r0.z = (bf2f(a[2]) + bf2f(b[2])) * inv;
    r0.w = (bf2f(a[3]) + bf2f(b[3])) * inv;
    r1.x = (bf2f(a[4]) + bf2f(b[4])) * inv;
    r1.y = (bf2f(a[5]) + bf2f(b[5])) * inv;
    r1.z = (bf2f(a[6]) + bf2f(b[6])) * inv;
    r1.w = (bf2f(a[7]) + bf2f(b[7])) * inv;
    *(float4*)(O + i0)     = r0;
    *(float4*)(O + i0 + 4) = r1;
}

extern "C" void kernel_launch(void* const* d_in, const int* in_sizes, int n_in,
                              void* d_out, int out_size, void* d_ws, size_t ws_size,
                              hipStream_t stream) {
    const float* q = (const float*)d_in[0];
    const float* k = (const float*)d_in[1];
    const float* v = (const float*)d_in[2];
    const float* s = (const float*)d_in[3];
    float* o = (float*)d_out;

    const size_t kv_elems = (size_t)BATCH * SEQ * DH;        // 4,194,304
    unsigned short* kws = (unsigned short*)d_ws;             // 8 MiB
    unsigned short* vws = kws + kv_elems;                    // 8 MiB
    unsigned short* o0b = vws + kv_elems;                    // 8 MiB bf16 partial
    unsigned short* o1b = o0b + kv_elems;                    // 8 MiB bf16 partial
    float* l0 = (float*)(o1b + kv_elems);                    // 256 KiB
    float* l1 = l0 + (size_t)BATCH * SEQ;                    // 256 KiB
    const size_t need = kv_elems * 2 * 4 + (size_t)BATCH * SEQ * 8;

    prep_kv<<<dim3(2 * BATCH * 64), dim3(256), 0, stream>>>(k, v, kws, vws);

    if (ws_size >= need) {
        // split-KV x2: 1024 blocks x 256 thr = 4 blocks/CU, 4 waves/SIMD
        attn_fwd<<<dim3(1024), dim3(256), 0, stream>>>(q, kws, vws, s, o, o0b, o1b, l0, l1, 2);
        merge_halves<<<dim3((BATCH * SEQ * DH) / (256 * 8)), dim3(256), 0, stream>>>(o, o0b, o1b, l0, l1);
    } else {
        // fallback: single pass, normalized inline
        attn_fwd<<<dim3(512), dim3(256), 0, stream>>>(q, kws, vws, s, o, nullptr, nullptr, nullptr, nullptr, 1);
    }
}

// Round 20
// 95.726 us; speedup vs baseline: 1.4329x; 1.4329x over previous
//
#include <hip/hip_runtime.h>
#include <hip/hip_bf16.h>

#define BATCH 16
#define SEQ   4096
#define DH    64
#define KVB   64
#define NT    (SEQ / KVB)       // 64 tiles
#define LDK   72                // prepass LDS stride (bf16 elems)

using frag   = __attribute__((ext_vector_type(8))) short;
using f32x16 = __attribute__((ext_vector_type(16))) float;
using u16x8  = __attribute__((ext_vector_type(8))) unsigned short;

__device__ __forceinline__ unsigned short f2bf(float x) {
    union { __hip_bfloat16 h; unsigned short u; } cv;
    cv.h = __float2bfloat16(x);
    return cv.u;
}
__device__ __forceinline__ float bf2f(unsigned short u) {
    union { unsigned int i; float f; } cv;
    cv.i = ((unsigned int)u) << 16;
    return cv.f;
}
__device__ __forceinline__ float fast_exp2(float x) {
#if __has_builtin(__builtin_amdgcn_exp2f)
    return __builtin_amdgcn_exp2f(x);
#else
    float r; asm("v_exp_f32 %0, %1" : "=v"(r) : "v"(x)); return r;
#endif
}
__device__ __forceinline__ unsigned int cvtpk_bf16(float lo, float hi) {
    unsigned int r;
    asm("v_cvt_pk_bf16_f32 %0, %1, %2" : "=v"(r) : "v"(lo), "v"(hi));
    return r;
}
__device__ __forceinline__ void glds16(const unsigned short* g, unsigned short* l) {
    __builtin_amdgcn_global_load_lds(
        (const __attribute__((address_space(1))) void*)g,
        (__attribute__((address_space(3))) void*)l, 16, 0, 0);
}
__device__ __forceinline__ f32x16 mfma32(frag a, frag b, f32x16 c) {
    return __builtin_amdgcn_mfma_f32_32x32x16_bf16(a, b, c, 0, 0, 0);
}

// ---------- fused pre-pass: K -> bf16 frag-major, V -> bf16 V^T frag-major ----------
__global__ __launch_bounds__(256) void prep_kv(const float* __restrict__ K,
                                               const float* __restrict__ V,
                                               unsigned short* __restrict__ Kws,
                                               unsigned short* __restrict__ Vws) {
    __shared__ unsigned short Ls[64 * LDK];
    const bool isV = blockIdx.x >= (BATCH * 64);
    const int  bt  = isV ? (blockIdx.x - BATCH * 64) : blockIdx.x;
    const int b = bt >> 6;
    const int t = bt & 63;
    const int i = threadIdx.x;
    {
        const int kv = i >> 2, db = (i & 3) * 16;
        const float* src = (isV ? V : K) + ((size_t)b * SEQ + (size_t)t * 64 + kv) * DH + db;
        float4 a = *(const float4*)(src);
        float4 c = *(const float4*)(src + 4);
        float4 d = *(const float4*)(src + 8);
        float4 e = *(const float4*)(src + 12);
        u16x8 w0, w1;
        w0[0]=f2bf(a.x); w0[1]=f2bf(a.y); w0[2]=f2bf(a.z); w0[3]=f2bf(a.w);
        w0[4]=f2bf(c.x); w0[5]=f2bf(c.y); w0[6]=f2bf(c.z); w0[7]=f2bf(c.w);
        w1[0]=f2bf(d.x); w1[1]=f2bf(d.y); w1[2]=f2bf(d.z); w1[3]=f2bf(d.w);
        w1[4]=f2bf(e.x); w1[5]=f2bf(e.y); w1[6]=f2bf(e.z); w1[7]=f2bf(e.w);
        *(u16x8*)&Ls[kv * LDK + db]     = w0;
        *(u16x8*)&Ls[kv * LDK + db + 8] = w1;
    }
    __syncthreads();
    if (!isV) {
        const int flat0 = i * 2;
        const int f     = flat0 >> 6;
        const int kb    = f & 1, kstep = f >> 1;
        const int l0    = flat0 & 63, l1 = l0 + 1;
        u16x8 o0 = *(const u16x8*)&Ls[(kb*32 + (l0&31)) * LDK + kstep*16 + (l0>>5)*8];
        u16x8 o1 = *(const u16x8*)&Ls[(kb*32 + (l1&31)) * LDK + kstep*16 + (l1>>5)*8];
        unsigned short* dst = Kws + ((((size_t)b*64 + t)*8 + f)*64 + l0)*8;
        *(u16x8*)dst       = o0;
        *(u16x8*)(dst + 8) = o1;
    } else {
        const int flat0 = i * 2;
        const int fv    = flat0 >> 6;
        const int kb    = fv >> 2, ks = (fv >> 1) & 1, dblk = fv & 1;
        u16x8 o0, o1;
        const int l0 = flat0 & 63, l1 = l0 + 1;
#pragma unroll
        for (int j = 0; j < 8; ++j)
            o0[j] = Ls[(kb*32 + ks*16 + (l0>>5)*8 + j) * LDK + dblk*32 + (l0&31)];
#pragma unroll
        for (int j = 0; j < 8; ++j)
            o1[j] = Ls[(kb*32 + ks*16 + (l1>>5)*8 + j) * LDK + dblk*32 + (l1&31)];
        unsigned short* dst = Vws + ((((size_t)b*64 + t)*8 + fv)*64 + l0)*8;
        *(u16x8*)dst       = o0;
        *(u16x8*)(dst + 8) = o1;
    }
}

// ---------- main attention kernel (QW=64: 2 q-subtiles per wave) ----------
// Each K-frag ds_read feeds 2 QK MFMAs, each V-frag feeds 2 PV MFMAs ->
// aggregate LDS-read traffic HALVES (the binding ~41us/CU pipe in r18).
// 2-wave blocks: wave 0 stages K, wave 1 stages V (8 glds/wave/tile).
// Split-KV x2 + bf16 unnormalized partials + merge. No setprio.
__global__ __launch_bounds__(128, 2) void attn_fwd(
    const float* __restrict__ Q, const unsigned short* __restrict__ Kws,
    const unsigned short* __restrict__ Vws, const float* __restrict__ S,
    float* __restrict__ O0, unsigned short* __restrict__ O0b,
    unsigned short* __restrict__ O1b,
    float* __restrict__ l0p, float* __restrict__ l1p, int nsplit)
{
    __shared__ unsigned short Kbuf[2][8 * 64 * 8];   // 16 KB
    __shared__ unsigned short Vbuf[2][8 * 64 * 8];   // 16 KB

    const int bid = blockIdx.x;
    const int xcd = bid & 7;
    int sub = bid >> 3;
    int half = 0;
    if (nsplit == 2) { half = sub & 1; sub >>= 1; }
    const int batch = xcd | ((sub & 1) << 3);
    const int qt    = sub >> 1;                      // 0..31, 128 q rows per block

    const int tid  = threadIdx.x;
    const int w    = tid >> 6;                       // wave 0/1, owns 64 q rows
    const int lane = tid & 63;
    const int c32  = lane & 31;
    const int hi   = lane >> 5;

    const int t0   = half * (NT / 2);
    const int ntil = NT / nsplit;

    const float sc = S[0] * 1.44269504088896340736f;

    const float*          Qb = Q   + ((size_t)batch * SEQ + (size_t)qt * 128 + w * 64) * DH;
    const unsigned short* Kg = Kws + (size_t)batch * 64 * 8 * 512;
    const unsigned short* Vg = Vws + (size_t)batch * 64 * 8 * 512;

    // Q B-frags for both q-subtiles: lane holds q-row qs*32+c32
    frag qF[2][4];
#pragma unroll
    for (int qs = 0; qs < 2; ++qs)
#pragma unroll
      for (int kstep = 0; kstep < 4; ++kstep) {
        const float* p = Qb + (qs * 32 + c32) * DH + kstep * 16 + hi * 8;
        float4 a = *(const float4*)p;
        float4 b = *(const float4*)(p + 4);
        frag f;
        f[0] = (short)f2bf(a.x * sc); f[1] = (short)f2bf(a.y * sc);
        f[2] = (short)f2bf(a.z * sc); f[3] = (short)f2bf(a.w * sc);
        f[4] = (short)f2bf(b.x * sc); f[5] = (short)f2bf(b.y * sc);
        f[6] = (short)f2bf(b.z * sc); f[7] = (short)f2bf(b.w * sc);
        qF[qs][kstep] = f;
      }

    frag ones;
#pragma unroll
    for (int j = 0; j < 8; ++j) ones[j] = (short)0x3F80;

    f32x16 o32[2][2];                 // [qs][dblk]
    f32x16 l32[2];                    // [qs]
#pragma unroll
    for (int qs = 0; qs < 2; ++qs) {
        o32[qs][0] = (f32x16)0.0f; o32[qs][1] = (f32x16)0.0f;
        l32[qs] = (f32x16)0.0f;
    }

    // staging: wave 0 -> 8 K frags, wave 1 -> 8 V frags
    const unsigned short* gsrc = (w == 0) ? Kg : Vg;
#pragma unroll
    for (int f = 0; f < 8; ++f) {
        unsigned short* lp = (w == 0) ? &Kbuf[0][f * 512] : &Vbuf[0][f * 512];
        glds16(gsrc + (size_t)t0 * 4096 + f * 512 + lane * 8, lp);
    }
    asm volatile("s_waitcnt vmcnt(0)" ::: "memory");
    __builtin_amdgcn_s_barrier();
    __builtin_amdgcn_sched_barrier(0);

    for (int tt = 0; tt < ntil; ++tt) {
        const int t   = t0 + tt;
        const int cur = tt & 1;
        if (tt + 1 < ntil) {     // async loads for t+1 fly across this tile's compute
#pragma unroll
            for (int f = 0; f < 8; ++f) {
                unsigned short* lp = (w == 0) ? &Kbuf[cur ^ 1][f * 512] : &Vbuf[cur ^ 1][f * 512];
                glds16(gsrc + (size_t)(t + 1) * 4096 + f * 512 + lane * 8, lp);
            }
        }

        // ---- QK^T: each kf read feeds BOTH q-subtiles ----
        f32x16 st[2][2];               // [qs][kb]
        st[0][0] = (f32x16)0.0f; st[0][1] = (f32x16)0.0f;
        st[1][0] = (f32x16)0.0f; st[1][1] = (f32x16)0.0f;
#pragma unroll
        for (int kstep = 0; kstep < 4; ++kstep)
#pragma unroll
          for (int kb = 0; kb < 2; ++kb) {
            frag kf = *(const frag*)&Kbuf[cur][(kstep * 2 + kb) * 512 + lane * 8];
            st[0][kb] = mfma32(kf, qF[0][kstep], st[0][kb]);
            st[1][kb] = mfma32(kf, qF[1][kstep], st[1][kb]);
          }

        // ---- native exp2 + cvt_pk + permlane32_swap -> PV A-frags ----
        frag pa[2][2][2];              // [qs][kb][ks]
#pragma unroll
        for (int qs = 0; qs < 2; ++qs)
#pragma unroll
          for (int kb = 0; kb < 2; ++kb) {
            float p[16];
#pragma unroll
            for (int r = 0; r < 16; ++r) p[r] = fast_exp2(st[qs][kb][r]);
            unsigned a0 = cvtpk_bf16(p[0],  p[1]),  a1 = cvtpk_bf16(p[2],  p[3]);
            unsigned b0 = cvtpk_bf16(p[4],  p[5]),  b1 = cvtpk_bf16(p[6],  p[7]);
            unsigned c0 = cvtpk_bf16(p[8],  p[9]),  c1 = cvtpk_bf16(p[10], p[11]);
            unsigned d0 = cvtpk_bf16(p[12], p[13]), d1 = cvtpk_bf16(p[14], p[15]);
            asm("v_permlane32_swap_b32 %0, %1" : "+v"(a0), "+v"(b0));
            asm("v_permlane32_swap_b32 %0, %1" : "+v"(a1), "+v"(b1));
            asm("v_permlane32_swap_b32 %0, %1" : "+v"(c0), "+v"(d0));
            asm("v_permlane32_swap_b32 %0, %1" : "+v"(c1), "+v"(d1));
            union { unsigned u[4]; frag f; } f0, f1;
            f0.u[0] = a0; f0.u[1] = a1; f0.u[2] = b0; f0.u[3] = b1;
            f1.u[0] = c0; f1.u[1] = c1; f1.u[2] = d0; f1.u[3] = d1;
            pa[qs][kb][0] = f0.f;
            pa[qs][kb][1] = f1.f;
          }

        // ---- row-sum (ones-MFMA) + PV: each vf read feeds BOTH q-subtiles ----
#pragma unroll
        for (int kb = 0; kb < 2; ++kb)
#pragma unroll
          for (int ks = 0; ks < 2; ++ks) {
            l32[0] = mfma32(pa[0][kb][ks], ones, l32[0]);
            l32[1] = mfma32(pa[1][kb][ks], ones, l32[1]);
#pragma unroll
            for (int dblk = 0; dblk < 2; ++dblk) {
                frag vf = *(const frag*)&Vbuf[cur][((kb * 2 + ks) * 2 + dblk) * 512 + lane * 8];
                o32[0][dblk] = mfma32(pa[0][kb][ks], vf, o32[0][dblk]);
                o32[1][dblk] = mfma32(pa[1][kb][ks], vf, o32[1][dblk]);
            }
          }

        asm volatile("s_waitcnt vmcnt(0)" ::: "memory");
        __builtin_amdgcn_s_barrier();
        __builtin_amdgcn_sched_barrier(0);
    }

    // ---- epilogue: row q = qs*32 + (r&3)+8*(r>>2)+4*hi, col d = dblk*32+c32 ----
    const size_t qrow0 = (size_t)batch * SEQ + (size_t)qt * 128 + w * 64;
    if (nsplit == 1) {
        float* Ob = O0 + qrow0 * DH;
#pragma unroll
        for (int qs = 0; qs < 2; ++qs) {
            float inv[16];
#pragma unroll
            for (int r = 0; r < 16; ++r) inv[r] = 1.0f / l32[qs][r];
#pragma unroll
            for (int dblk = 0; dblk < 2; ++dblk)
#pragma unroll
              for (int r = 0; r < 16; ++r) {
                const int qrow = qs * 32 + (r & 3) + 8 * (r >> 2) + 4 * hi;
                Ob[qrow * DH + dblk * 32 + c32] = o32[qs][dblk][r] * inv[r];
              }
        }
    } else {
        unsigned short* Ob = (half ? O1b : O0b) + qrow0 * DH;
        float* lb = (half ? l1p : l0p) + qrow0;
#pragma unroll
        for (int qs = 0; qs < 2; ++qs) {
#pragma unroll
            for (int dblk = 0; dblk < 2; ++dblk)
#pragma unroll
              for (int r = 0; r < 16; ++r) {
                const int qrow = qs * 32 + (r & 3) + 8 * (r >> 2) + 4 * hi;
                Ob[qrow * DH + dblk * 32 + c32] = f2bf(o32[qs][dblk][r]);
              }
            if (c32 == 0) {
#pragma unroll
                for (int r = 0; r < 16; ++r) {
                    const int qrow = qs * 32 + (r & 3) + 8 * (r >> 2) + 4 * hi;
                    lb[qrow] = l32[qs][r];
                }
            }
        }
    }
}

// ---------- merge: O = (bf2f(O0b) + bf2f(O1b)) / (l0 + l1) ----------
__global__ __launch_bounds__(256) void merge_halves(
    float* __restrict__ O, const unsigned short* __restrict__ O0b,
    const unsigned short* __restrict__ O1b,
    const float* __restrict__ l0, const float* __restrict__ l1)
{
    const size_t i0  = ((size_t)blockIdx.x * 256 + threadIdx.x) * 8;
    const size_t row = i0 >> 6;
    const float inv  = 1.0f / (l0[row] + l1[row]);
    u16x8 a = *(const u16x8*)(O0b + i0);
    u16x8 b = *(const u16x8*)(O1b + i0);
    float4 r0, r1;
    r0.x = (bf2f(a[0]) + bf2f(b[0])) * inv;
    r0.y = (bf2f(a[1]) + bf2f(b[1])) * inv;
    r0.z = (bf2f(a[2]) + bf2f(b[2])) * inv;
    r0.w = (bf2f(a[3]) + bf2f(b[3])) * inv;
    r1.x = (bf2f(a[4]) + bf2f(b[4])) * inv;
    r1.y = (bf2f(a[5]) + bf2f(b[5])) * inv;
    r1.z = (bf2f(a[6]) + bf2f(b[6])) * inv;
    r1.w = (bf2f(a[7]) + bf2f(b[7])) * inv;
    *(float4*)(O + i0)     = r0;
    *(float4*)(O + i0 + 4) = r1;
}

extern "C" void kernel_launch(void* const* d_in, const int* in_sizes, int n_in,
                              void* d_out, int out_size, void* d_ws, size_t ws_size,
                              hipStream_t stream) {
    const float* q = (const float*)d_in[0];
    const float* k = (const float*)d_in[1];
    const float* v = (const float*)d_in[2];
    const float* s = (const float*)d_in[3];
    float* o = (float*)d_out;

    const size_t kv_elems = (size_t)BATCH * SEQ * DH;        // 4,194,304
    unsigned short* kws = (unsigned short*)d_ws;             // 8 MiB
    unsigned short* vws = kws + kv_elems;                    // 8 MiB
    unsigned short* o0b = vws + kv_elems;                    // 8 MiB bf16 partial
    unsigned short* o1b = o0b + kv_elems;                    // 8 MiB bf16 partial
    float* l0 = (float*)(o1b + kv_elems);                    // 256 KiB
    float* l1 = l0 + (size_t)BATCH * SEQ;                    // 256 KiB
    const size_t need = kv_elems * 2 * 4 + (size_t)BATCH * SEQ * 8;

    prep_kv<<<dim3(2 * BATCH * 64), dim3(256), 0, stream>>>(k, v, kws, vws);

    if (ws_size >= need) {
        // split-KV x2: 1024 blocks x 128 thr = 4 blocks/CU, 8 waves/CU
        attn_fwd<<<dim3(1024), dim3(128), 0, stream>>>(q, kws, vws, s, o, o0b, o1b, l0, l1, 2);
        merge_halves<<<dim3((BATCH * SEQ * DH) / (256 * 8)), dim3(256), 0, stream>>>(o, o0b, o1b, l0, l1);
    } else {
        // fallback: single pass, normalized inline
        attn_fwd<<<dim3(512), dim3(128), 0, stream>>>(q, kws, vws, s, o, nullptr, nullptr, nullptr, nullptr, 1);
    }
}

// Round 21
// 94.468 us; speedup vs baseline: 1.4520x; 1.0133x over previous
//
#include <hip/hip_runtime.h>
#include <hip/hip_bf16.h>

#define BATCH 16
#define SEQ   4096
#define DH    64
#define KVB   64
#define NT    (SEQ / KVB)       // 64 tiles
#define LDK   72                // prepass LDS stride (bf16 elems)

using frag   = __attribute__((ext_vector_type(8))) short;
using f32x16 = __attribute__((ext_vector_type(16))) float;
using u16x8  = __attribute__((ext_vector_type(8))) unsigned short;

__device__ __forceinline__ unsigned short f2bf(float x) {
    union { __hip_bfloat16 h; unsigned short u; } cv;
    cv.h = __float2bfloat16(x);
    return cv.u;
}
__device__ __forceinline__ float bf2f(unsigned short u) {
    union { unsigned int i; float f; } cv;
    cv.i = ((unsigned int)u) << 16;
    return cv.f;
}
__device__ __forceinline__ float fast_exp2(float x) {
#if __has_builtin(__builtin_amdgcn_exp2f)
    return __builtin_amdgcn_exp2f(x);
#else
    float r; asm("v_exp_f32 %0, %1" : "=v"(r) : "v"(x)); return r;
#endif
}
__device__ __forceinline__ unsigned int cvtpk_bf16(float lo, float hi) {
    unsigned int r;
    asm("v_cvt_pk_bf16_f32 %0, %1, %2" : "=v"(r) : "v"(lo), "v"(hi));
    return r;
}
__device__ __forceinline__ void glds16(const unsigned short* g, unsigned short* l) {
    __builtin_amdgcn_global_load_lds(
        (const __attribute__((address_space(1))) void*)g,
        (__attribute__((address_space(3))) void*)l, 16, 0, 0);
}
__device__ __forceinline__ f32x16 mfma32(frag a, frag b, f32x16 c) {
    return __builtin_amdgcn_mfma_f32_32x32x16_bf16(a, b, c, 0, 0, 0);
}

// ---------- fused pre-pass: K -> bf16 frag-major, V -> bf16 V^T frag-major ----------
__global__ __launch_bounds__(256) void prep_kv(const float* __restrict__ K,
                                               const float* __restrict__ V,
                                               unsigned short* __restrict__ Kws,
                                               unsigned short* __restrict__ Vws) {
    __shared__ unsigned short Ls[64 * LDK];
    const bool isV = blockIdx.x >= (BATCH * 64);
    const int  bt  = isV ? (blockIdx.x - BATCH * 64) : blockIdx.x;
    const int b = bt >> 6;
    const int t = bt & 63;
    const int i = threadIdx.x;
    {
        const int kv = i >> 2, db = (i & 3) * 16;
        const float* src = (isV ? V : K) + ((size_t)b * SEQ + (size_t)t * 64 + kv) * DH + db;
        float4 a = *(const float4*)(src);
        float4 c = *(const float4*)(src + 4);
        float4 d = *(const float4*)(src + 8);
        float4 e = *(const float4*)(src + 12);
        u16x8 w0, w1;
        w0[0]=f2bf(a.x); w0[1]=f2bf(a.y); w0[2]=f2bf(a.z); w0[3]=f2bf(a.w);
        w0[4]=f2bf(c.x); w0[5]=f2bf(c.y); w0[6]=f2bf(c.z); w0[7]=f2bf(c.w);
        w1[0]=f2bf(d.x); w1[1]=f2bf(d.y); w1[2]=f2bf(d.z); w1[3]=f2bf(d.w);
        w1[4]=f2bf(e.x); w1[5]=f2bf(e.y); w1[6]=f2bf(e.z); w1[7]=f2bf(e.w);
        *(u16x8*)&Ls[kv * LDK + db]     = w0;
        *(u16x8*)&Ls[kv * LDK + db + 8] = w1;
    }
    __syncthreads();
    if (!isV) {
        const int flat0 = i * 2;
        const int f     = flat0 >> 6;
        const int kb    = f & 1, kstep = f >> 1;
        const int l0    = flat0 & 63, l1 = l0 + 1;
        u16x8 o0 = *(const u16x8*)&Ls[(kb*32 + (l0&31)) * LDK + kstep*16 + (l0>>5)*8];
        u16x8 o1 = *(const u16x8*)&Ls[(kb*32 + (l1&31)) * LDK + kstep*16 + (l1>>5)*8];
        unsigned short* dst = Kws + ((((size_t)b*64 + t)*8 + f)*64 + l0)*8;
        *(u16x8*)dst       = o0;
        *(u16x8*)(dst + 8) = o1;
    } else {
        const int flat0 = i * 2;
        const int fv    = flat0 >> 6;
        const int kb    = fv >> 2, ks = (fv >> 1) & 1, dblk = fv & 1;
        u16x8 o0, o1;
        const int l0 = flat0 & 63, l1 = l0 + 1;
#pragma unroll
        for (int j = 0; j < 8; ++j)
            o0[j] = Ls[(kb*32 + ks*16 + (l0>>5)*8 + j) * LDK + dblk*32 + (l0&31)];
#pragma unroll
        for (int j = 0; j < 8; ++j)
            o1[j] = Ls[(kb*32 + ks*16 + (l1>>5)*8 + j) * LDK + dblk*32 + (l1&31)];
        unsigned short* dst = Vws + ((((size_t)b*64 + t)*8 + fv)*64 + l0)*8;
        *(u16x8*)dst       = o0;
        *(u16x8*)(dst + 8) = o1;
    }
}

// ---------- main attention kernel ----------
// r18 structure (QW=32, 4-wave 256-thr blocks, split-KV x2, glds dbuf,
// one barrier/tile, bf16 unnormalized partials, no setprio) with the
// ones-MFMA row-sum replaced by lane-local VALU adds on live p[] values:
// lane (c32,hi) holds half of q-row c32's P; accumulate own half across
// tiles in ONE scalar, single __shfl_xor(,32) at the end. -4 MFMA/tile,
// -15 registers.
__global__ __launch_bounds__(256, 4) void attn_fwd(
    const float* __restrict__ Q, const unsigned short* __restrict__ Kws,
    const unsigned short* __restrict__ Vws, const float* __restrict__ S,
    float* __restrict__ O0, unsigned short* __restrict__ O0b,
    unsigned short* __restrict__ O1b,
    float* __restrict__ l0p, float* __restrict__ l1p, int nsplit)
{
    __shared__ unsigned short Kbuf[2][8 * 64 * 8];   // 16 KB
    __shared__ unsigned short Vbuf[2][8 * 64 * 8];   // 16 KB

    const int bid = blockIdx.x;
    const int xcd = bid & 7;
    int sub = bid >> 3;
    int half = 0;
    if (nsplit == 2) { half = sub & 1; sub >>= 1; }
    const int batch = xcd | ((sub & 1) << 3);
    const int qt    = sub >> 1;                      // 0..31, 128 q rows per block

    const int tid  = threadIdx.x;
    const int w    = tid >> 6;                       // wave 0..3, owns 32 q rows
    const int lane = tid & 63;
    const int c32  = lane & 31;
    const int hi   = lane >> 5;

    const int t0   = half * (NT / 2);
    const int ntil = NT / nsplit;

    const float sc = S[0] * 1.44269504088896340736f;

    const float*          Qb = Q   + ((size_t)batch * SEQ + (size_t)qt * 128 + w * 32) * DH;
    const unsigned short* Kg = Kws + (size_t)batch * 64 * 8 * 512;
    const unsigned short* Vg = Vws + (size_t)batch * 64 * 8 * 512;

    frag qF[4];
#pragma unroll
    for (int kstep = 0; kstep < 4; ++kstep) {
        const float* p = Qb + c32 * DH + kstep * 16 + hi * 8;
        float4 a = *(const float4*)p;
        float4 b = *(const float4*)(p + 4);
        frag f;
        f[0] = (short)f2bf(a.x * sc); f[1] = (short)f2bf(a.y * sc);
        f[2] = (short)f2bf(a.z * sc); f[3] = (short)f2bf(a.w * sc);
        f[4] = (short)f2bf(b.x * sc); f[5] = (short)f2bf(b.y * sc);
        f[6] = (short)f2bf(b.z * sc); f[7] = (short)f2bf(b.w * sc);
        qF[kstep] = f;
    }

    f32x16 o32[2];
    o32[0] = (f32x16)0.0f; o32[1] = (f32x16)0.0f;
    float l_own = 0.0f;        // running row-sum, own (c32,hi) half

    // staging: wave w stages K frags {2w,2w+1} and V frags {2w,2w+1}
    const int fbase = w * 2;
#pragma unroll
    for (int f = 0; f < 2; ++f) {
        glds16(Kg + (size_t)t0 * 4096 + (fbase + f) * 512 + lane * 8, &Kbuf[0][(fbase + f) * 512]);
        glds16(Vg + (size_t)t0 * 4096 + (fbase + f) * 512 + lane * 8, &Vbuf[0][(fbase + f) * 512]);
    }
    asm volatile("s_waitcnt vmcnt(0)" ::: "memory");
    __builtin_amdgcn_s_barrier();
    __builtin_amdgcn_sched_barrier(0);

    for (int tt = 0; tt < ntil; ++tt) {
        const int t   = t0 + tt;
        const int cur = tt & 1;
        if (tt + 1 < ntil) {     // async loads for t+1 fly across this tile's compute
#pragma unroll
            for (int f = 0; f < 2; ++f) {
                glds16(Kg + (size_t)(t + 1) * 4096 + (fbase + f) * 512 + lane * 8,
                       &Kbuf[cur ^ 1][(fbase + f) * 512]);
                glds16(Vg + (size_t)(t + 1) * 4096 + (fbase + f) * 512 + lane * 8,
                       &Vbuf[cur ^ 1][(fbase + f) * 512]);
            }
        }

        // ---- QK^T (swapped, 32x32x16): lane holds P^T[kv][q=c32] ----
        f32x16 st[2];
        st[0] = (f32x16)0.0f; st[1] = (f32x16)0.0f;
#pragma unroll
        for (int kstep = 0; kstep < 4; ++kstep)
#pragma unroll
          for (int kb = 0; kb < 2; ++kb) {
            frag kf = *(const frag*)&Kbuf[cur][(kstep * 2 + kb) * 512 + lane * 8];
            st[kb] = mfma32(kf, qF[kstep], st[kb]);
          }

        // ---- native exp2 + VALU row-sum + cvt_pk + permlane -> PV A-frags ----
        frag pa[2][2];
        float rs = 0.0f;
#pragma unroll
        for (int kb = 0; kb < 2; ++kb) {
            float p[16];
#pragma unroll
            for (int r = 0; r < 16; ++r) p[r] = fast_exp2(st[kb][r]);
#pragma unroll
            for (int r = 0; r < 16; ++r) rs += p[r];
            unsigned a0 = cvtpk_bf16(p[0],  p[1]),  a1 = cvtpk_bf16(p[2],  p[3]);
            unsigned b0 = cvtpk_bf16(p[4],  p[5]),  b1 = cvtpk_bf16(p[6],  p[7]);
            unsigned c0 = cvtpk_bf16(p[8],  p[9]),  c1 = cvtpk_bf16(p[10], p[11]);
            unsigned d0 = cvtpk_bf16(p[12], p[13]), d1 = cvtpk_bf16(p[14], p[15]);
            asm("v_permlane32_swap_b32 %0, %1" : "+v"(a0), "+v"(b0));
            asm("v_permlane32_swap_b32 %0, %1" : "+v"(a1), "+v"(b1));
            asm("v_permlane32_swap_b32 %0, %1" : "+v"(c0), "+v"(d0));
            asm("v_permlane32_swap_b32 %0, %1" : "+v"(c1), "+v"(d1));
            union { unsigned u[4]; frag f; } f0, f1;
            f0.u[0] = a0; f0.u[1] = a1; f0.u[2] = b0; f0.u[3] = b1;
            f1.u[0] = c0; f1.u[1] = c1; f1.u[2] = d0; f1.u[3] = d1;
            pa[kb][0] = f0.f;
            pa[kb][1] = f1.f;
        }
        l_own += rs;

        // ---- PV only (row-sum MFMAs deleted) ----
#pragma unroll
        for (int kb = 0; kb < 2; ++kb)
#pragma unroll
          for (int ks = 0; ks < 2; ++ks)
#pragma unroll
            for (int dblk = 0; dblk < 2; ++dblk) {
                frag vf = *(const frag*)&Vbuf[cur][((kb * 2 + ks) * 2 + dblk) * 512 + lane * 8];
                o32[dblk] = mfma32(pa[kb][ks], vf, o32[dblk]);
            }

        asm volatile("s_waitcnt vmcnt(0)" ::: "memory");
        __builtin_amdgcn_s_barrier();
        __builtin_amdgcn_sched_barrier(0);
    }

    // full row-sum for q-row c32 (both hi lanes get it)
    const float l_all = l_own + __shfl_xor(l_own, 32);

    // ---- epilogue: row q = (r&3)+8*(r>>2)+4*hi, col d = dblk*32+c32 ----
    const size_t qrow0 = (size_t)batch * SEQ + (size_t)qt * 128 + w * 32;
    if (nsplit == 1) {
        // broadcast per-row l via LDS (Kbuf dead after final barrier)
        float* Lf = (float*)&Kbuf[0][0];
        if (hi == 0) Lf[w * 32 + c32] = l_all;
        __syncthreads();
        float* Ob = O0 + qrow0 * DH;
#pragma unroll
        for (int dblk = 0; dblk < 2; ++dblk)
#pragma unroll
          for (int r = 0; r < 16; ++r) {
            const int qrow = (r & 3) + 8 * (r >> 2) + 4 * hi;
            Ob[qrow * DH + dblk * 32 + c32] = o32[dblk][r] / Lf[w * 32 + qrow];
          }
    } else {
        unsigned short* Ob = (half ? O1b : O0b) + qrow0 * DH;
        float* lb = (half ? l1p : l0p) + qrow0;
#pragma unroll
        for (int dblk = 0; dblk < 2; ++dblk)
#pragma unroll
          for (int r = 0; r < 16; ++r) {
            const int qrow = (r & 3) + 8 * (r >> 2) + 4 * hi;
            Ob[qrow * DH + dblk * 32 + c32] = f2bf(o32[dblk][r]);
          }
        if (hi == 0) lb[c32] = l_all;   // lane's own q-row
    }
}

// ---------- merge: O = (bf2f(O0b) + bf2f(O1b)) / (l0 + l1) ----------
__global__ __launch_bounds__(256) void merge_halves(
    float* __restrict__ O, const unsigned short* __restrict__ O0b,
    const unsigned short* __restrict__ O1b,
    const float* __restrict__ l0, const float* __restrict__ l1)
{
    const size_t i0  = ((size_t)blockIdx.x * 256 + threadIdx.x) * 8;
    const size_t row = i0 >> 6;
    const float inv  = 1.0f / (l0[row] + l1[row]);
    u16x8 a = *(const u16x8*)(O0b + i0);
    u16x8 b = *(const u16x8*)(O1b + i0);
    float4 r0, r1;
    r0.x = (bf2f(a[0]) + bf2f(b[0])) * inv;
    r0.y = (bf2f(a[1]) + bf2f(b[1])) * inv;
    r0.z = (bf2f(a[2]) + bf2f(b[2])) * inv;
    r0.w = (bf2f(a[3]) + bf2f(b[3])) * inv;
    r1.x = (bf2f(a[4]) + bf2f(b[4])) * inv;
    r1.y = (bf2f(a[5]) + bf2f(b[5])) * inv;
    r1.z = (bf2f(a[6]) + bf2f(b[6])) * inv;
    r1.w = (bf2f(a[7]) + bf2f(b[7])) * inv;
    *(float4*)(O + i0)     = r0;
    *(float4*)(O + i0 + 4) = r1;
}

extern "C" void kernel_launch(void* const* d_in, const int* in_sizes, int n_in,
                              void* d_out, int out_size, void* d_ws, size_t ws_size,
                              hipStream_t stream) {
    const float* q = (const float*)d_in[0];
    const float* k = (const float*)d_in[1];
    const float* v = (const float*)d_in[2];
    const float* s = (const float*)d_in[3];
    float* o = (float*)d_out;

    const size_t kv_elems = (size_t)BATCH * SEQ * DH;        // 4,194,304
    unsigned short* kws = (unsigned short*)d_ws;             // 8 MiB
    unsigned short* vws = kws + kv_elems;                    // 8 MiB
    unsigned short* o0b = vws + kv_elems;                    // 8 MiB bf16 partial
    unsigned short* o1b = o0b + kv_elems;                    // 8 MiB bf16 partial
    float* l0 = (float*)(o1b + kv_elems);                    // 256 KiB
    float* l1 = l0 + (size_t)BATCH * SEQ;                    // 256 KiB
    const size_t need = kv_elems * 2 * 4 + (size_t)BATCH * SEQ * 8;

    prep_kv<<<dim3(2 * BATCH * 64), dim3(256), 0, stream>>>(k, v, kws, vws);

    if (ws_size >= need) {
        // split-KV x2: 1024 blocks x 256 thr = 4 blocks/CU, 16 waves/CU
        attn_fwd<<<dim3(1024), dim3(256), 0, stream>>>(q, kws, vws, s, o, o0b, o1b, l0, l1, 2);
        merge_halves<<<dim3((BATCH * SEQ * DH) / (256 * 8)), dim3(256), 0, stream>>>(o, o0b, o1b, l0, l1);
    } else {
        // fallback: single pass, normalized inline
        attn_fwd<<<dim3(512), dim3(256), 0, stream>>>(q, kws, vws, s, o, nullptr, nullptr, nullptr, nullptr, 1);
    }
}